// Round 1
// baseline (866.969 us; speedup 1.0000x reference)
//
#include <hip/hip_runtime.h>
#include <stdint.h>

typedef __attribute__((ext_vector_type(8))) short v8s;
typedef __attribute__((ext_vector_type(4))) float v4f;

#define NBATCH 32
#define SEQ 2048
#define DHEAD 64

__device__ __forceinline__ unsigned short f2bf(float f) {
  unsigned int x = __float_as_uint(f);
  x += 0x7fffu + ((x >> 16) & 1u);
  return (unsigned short)(x >> 16);
}

// ---- prepass: fp32 -> bf16 copy (Q, K) ----
__global__ void cvt_bf16_k(const float* __restrict__ src,
                           unsigned short* __restrict__ dst, int n4) {
  int i = blockIdx.x * blockDim.x + threadIdx.x;
  if (i >= n4) return;
  float4 v = ((const float4*)src)[i];
  ushort4 o;
  o.x = f2bf(v.x); o.y = f2bf(v.y); o.z = f2bf(v.z); o.w = f2bf(v.w);
  ((ushort4*)dst)[i] = o;
}

// ---- prepass: V (n,k,d) -> Vt (n,d,k) bf16 ----
__global__ void vtrans_k(const float* __restrict__ V,
                         unsigned short* __restrict__ Vt) {
  __shared__ float tile[64][65];
  int n = blockIdx.y, k0 = blockIdx.x * 64;
  int t = threadIdx.x;
  int c = t & 63, rb = t >> 6;
#pragma unroll
  for (int it = 0; it < 16; ++it) {
    int r = it * 4 + rb;
    tile[r][c] = V[((size_t)(n * SEQ + k0 + r)) * DHEAD + c];
  }
  __syncthreads();
#pragma unroll
  for (int it = 0; it < 16; ++it) {
    int d = it * 4 + rb;
    Vt[((size_t)(n * DHEAD + d)) * SEQ + k0 + c] = f2bf(tile[c][d]);
  }
}

// ---- prepass: attn_mask (m,k) int -> transposed bits amT[k][m/32] ----
__global__ void pack_am_k(const int* __restrict__ am, unsigned int* __restrict__ amT) {
  int tid = blockIdx.x * blockDim.x + threadIdx.x;  // 131072 threads
  int k = tid & (SEQ - 1), w = tid >> 11;
  unsigned int bits = 0;
#pragma unroll 4
  for (int i = 0; i < 32; ++i)
    bits |= (am[(size_t)(w * 32 + i) * SEQ + k] != 0 ? 1u : 0u) << i;
  amT[k * 64 + w] = bits;
}

// ---- prepass: key_padding_mask (n,k) int -> bits kpmB[n][k/32] ----
__global__ void pack_kpm_k(const int* __restrict__ kpm, unsigned int* __restrict__ kpmB) {
  int tid = blockIdx.x * blockDim.x + threadIdx.x;  // 2048 threads
  if (tid >= NBATCH * 64) return;
  int n = tid >> 6, w = tid & 63;
  unsigned int bits = 0;
#pragma unroll 4
  for (int i = 0; i < 32; ++i)
    bits |= (kpm[n * SEQ + w * 32 + i] != 0 ? 1u : 0u) << i;
  kpmB[n * 64 + w] = bits;
}

// ---- main fused attention kernel ----
// block = 512 threads (8 waves). Each block: one batch n, 16 query rows.
// Wave w owns key columns [256w, 256w+256).
__global__ __launch_bounds__(512, 2)
void attn_main_k(const unsigned short* __restrict__ Qb,
                 const unsigned short* __restrict__ Kb,
                 const unsigned short* __restrict__ Vt,
                 const unsigned int* __restrict__ amT,
                 const unsigned int* __restrict__ kpmB,
                 float* __restrict__ outO, float* __restrict__ outW) {
  __shared__ __align__(16) char smem[65536];  // P(bf16) 16 rows x 2048, XOR-swizzled

  const int n = blockIdx.y;
  const int row0 = blockIdx.x * 16;
  const int tid = threadIdx.x;
  const int wave = tid >> 6, lane = tid & 63;
  const int quad = lane >> 4, lq = lane & 15;
  const int colw = wave * 256;

  // Q A-fragments: A[m=lq][k = quad*8 + j] (+32 for second MFMA)
  const unsigned short* qp = Qb + ((size_t)(n * SEQ + row0 + lq)) * DHEAD + quad * 8;
  v8s a0 = *(const v8s*)qp;
  v8s a1 = *(const v8s*)(qp + 32);

  float p[64];
  float rsum[4] = {0.f, 0.f, 0.f, 0.f};
  const int amsh = row0 & 31;
  const int amw = row0 >> 5;

  // ---- Phase 1: S = QK^T/8, mask, exp; keep P in regs; accumulate row sums
#pragma unroll
  for (int kt = 0; kt < 16; ++kt) {
    const int col = colw + kt * 16 + lq;
    const unsigned short* kp = Kb + ((size_t)(n * SEQ + col)) * DHEAD + quad * 8;
    v8s b0 = *(const v8s*)kp;
    v8s b1 = *(const v8s*)(kp + 32);
    v4f c = {0.f, 0.f, 0.f, 0.f};
    c = __builtin_amdgcn_mfma_f32_16x16x32_bf16(a0, b0, c, 0, 0, 0);
    c = __builtin_amdgcn_mfma_f32_16x16x32_bf16(a1, b1, c, 0, 0, 0);
    unsigned int kbit = (kpmB[n * 64 + (col >> 5)] >> (col & 31)) & 1u;
    unsigned int abits = amT[col * 64 + amw] >> amsh;
#pragma unroll
    for (int r = 0; r < 4; ++r) {
      unsigned int msk = kbit | ((abits >> (quad * 4 + r)) & 1u);
      float e = msk ? 0.f : __expf(c[r] * 0.125f);
      p[kt * 4 + r] = e;
      rsum[r] += e;
    }
  }

  // ---- Row-sum reduce: 16 lanes of quad -> all lanes; then cross-wave via LDS
#pragma unroll
  for (int r = 0; r < 4; ++r) {
    float s = rsum[r];
    s += __shfl_xor(s, 1);
    s += __shfl_xor(s, 2);
    s += __shfl_xor(s, 4);
    s += __shfl_xor(s, 8);
    rsum[r] = s;
  }
  float* wsum = (float*)smem;  // [8 waves][16 rows]
  if (lq == 0) {
#pragma unroll
    for (int r = 0; r < 4; ++r) wsum[wave * 16 + quad * 4 + r] = rsum[r];
  }
  __syncthreads();
  float rinv[4];
#pragma unroll
  for (int r = 0; r < 4; ++r) {
    float s = 0.f;
#pragma unroll
    for (int w = 0; w < 8; ++w) s += wsum[w * 16 + quad * 4 + r];
    rinv[r] = 1.0f / s;
  }
  __syncthreads();  // everyone done with wsum before P overwrites smem

  // ---- Phase 2: normalize, write attn_weights (fp32), stash bf16 P in LDS
  // LDS layout: byte = row*4096 + ((col/8 ^ (row&7))*16) + (col&7)*2  (XOR swizzle)
  float* wrow = outW + ((size_t)(n * SEQ + row0)) * SEQ;
#pragma unroll
  for (int kt = 0; kt < 16; ++kt) {
    const int colL = colw + kt * 16 + lq;
#pragma unroll
    for (int r = 0; r < 4; ++r) {
      const int rr = quad * 4 + r;
      float pn = p[kt * 4 + r] * rinv[r];
      wrow[(size_t)rr * SEQ + colL] = pn;
      *(unsigned short*)(smem + rr * 4096 +
                         ((((colL >> 3) ^ (rr & 7)) << 4) | ((colL & 7) << 1))) = f2bf(pn);
    }
  }
  __syncthreads();

  // ---- Phase 3: O_partial = P(16x256) x V(256x64) via MFMA
  v4f acc[4] = {{0.f,0.f,0.f,0.f},{0.f,0.f,0.f,0.f},{0.f,0.f,0.f,0.f},{0.f,0.f,0.f,0.f}};
#pragma unroll
  for (int ch = 0; ch < 8; ++ch) {
    const int cb = colw + ch * 32;
    // A[m=lq][k = quad*8 + j] from swizzled LDS (16B aligned)
    v8s ap = *(const v8s*)(smem + lq * 4096 + (((((cb >> 3) + quad) ^ (lq & 7)) << 4)));
#pragma unroll
    for (int dt = 0; dt < 4; ++dt) {
      const unsigned short* vp =
          Vt + ((size_t)(n * DHEAD + dt * 16 + lq)) * SEQ + cb + quad * 8;
      v8s bp = *(const v8s*)vp;
      acc[dt] = __builtin_amdgcn_mfma_f32_16x16x32_bf16(ap, bp, acc[dt], 0, 0, 0);
    }
  }
  __syncthreads();

  // ---- Phase 4: cross-wave O reduction (8 partials of 16x64) through LDS
  float* olds = (float*)smem;  // [8][16][68] padded
#pragma unroll
  for (int dt = 0; dt < 4; ++dt)
#pragma unroll
    for (int r = 0; r < 4; ++r)
      olds[wave * 1088 + (quad * 4 + r) * 68 + dt * 16 + lq] = acc[dt][r];
  __syncthreads();
#pragma unroll
  for (int s = 0; s < 2; ++s) {
    int e = tid + s * 512;
    int row = e >> 6, d = e & 63;
    float a = 0.f;
#pragma unroll
    for (int w = 0; w < 8; ++w) a += olds[w * 1088 + row * 68 + d];
    outO[((size_t)(n * SEQ + row0 + row)) * DHEAD + d] = a;
  }
}

extern "C" void kernel_launch(void* const* d_in, const int* in_sizes, int n_in,
                              void* d_out, int out_size, void* d_ws, size_t ws_size,
                              hipStream_t stream) {
  const float* Q = (const float*)d_in[0];
  const float* K = (const float*)d_in[1];
  const float* V = (const float*)d_in[2];
  const int* kpm = (const int*)d_in[3];
  const int* am = (const int*)d_in[4];

  float* outO = (float*)d_out;
  float* outW = outO + (size_t)NBATCH * SEQ * DHEAD;  // 4,194,304 floats

  char* ws = (char*)d_ws;
  unsigned short* Qb = (unsigned short*)ws;                       // 8 MiB
  unsigned short* Kb = (unsigned short*)(ws + (8u << 20));        // 8 MiB
  unsigned short* Vt = (unsigned short*)(ws + (16u << 20));       // 8 MiB
  unsigned int* amT = (unsigned int*)(ws + (24u << 20));          // 512 KiB
  unsigned int* kpmB = (unsigned int*)(ws + (24u << 20) + (1u << 19));  // 8 KiB

  const int n4 = NBATCH * SEQ * DHEAD / 4;  // 1,048,576
  cvt_bf16_k<<<n4 / 256, 256, 0, stream>>>(Q, Qb, n4);
  cvt_bf16_k<<<n4 / 256, 256, 0, stream>>>(K, Kb, n4);
  vtrans_k<<<dim3(SEQ / 64, NBATCH), 256, 0, stream>>>(V, Vt);
  pack_am_k<<<(SEQ * 64) / 256, 256, 0, stream>>>(am, amT);
  pack_kpm_k<<<8, 256, 0, stream>>>(kpm, kpmB);
  attn_main_k<<<dim3(SEQ / 16, NBATCH), 512, 0, stream>>>(Qb, Kb, Vt, amT, kpmB,
                                                          outO, outW);
}

// Round 2
// 814.740 us; speedup vs baseline: 1.0641x; 1.0641x over previous
//
#include <hip/hip_runtime.h>
#include <stdint.h>

typedef __attribute__((ext_vector_type(8))) short v8s;
typedef __attribute__((ext_vector_type(4))) float v4f;

#define NBATCH 32
#define SEQ 2048
#define DHEAD 64

__device__ __forceinline__ unsigned short f2bf(float f) {
  unsigned int x = __float_as_uint(f);
  x += 0x7fffu + ((x >> 16) & 1u);
  return (unsigned short)(x >> 16);
}

__device__ __forceinline__ float bf2f(short s) {
  return __uint_as_float(((unsigned int)(unsigned short)s) << 16);
}

// ---- prepass: fp32 -> bf16 copy (Q, K) ----
__global__ void cvt_bf16_k(const float* __restrict__ src,
                           unsigned short* __restrict__ dst, int n4) {
  int i = blockIdx.x * blockDim.x + threadIdx.x;
  if (i >= n4) return;
  float4 v = ((const float4*)src)[i];
  ushort4 o;
  o.x = f2bf(v.x); o.y = f2bf(v.y); o.z = f2bf(v.z); o.w = f2bf(v.w);
  ((ushort4*)dst)[i] = o;
}

// ---- prepass: V (n,k,d) -> Vt (n,d,k) bf16 ----
__global__ void vtrans_k(const float* __restrict__ V,
                         unsigned short* __restrict__ Vt) {
  __shared__ float tile[64][65];
  int n = blockIdx.y, k0 = blockIdx.x * 64;
  int t = threadIdx.x;
  int c = t & 63, rb = t >> 6;
#pragma unroll
  for (int it = 0; it < 16; ++it) {
    int r = it * 4 + rb;
    tile[r][c] = V[((size_t)(n * SEQ + k0 + r)) * DHEAD + c];
  }
  __syncthreads();
#pragma unroll
  for (int it = 0; it < 16; ++it) {
    int d = it * 4 + rb;
    Vt[((size_t)(n * DHEAD + d)) * SEQ + k0 + c] = f2bf(tile[c][d]);
  }
}

// ---- prepass: attn_mask (m,k) int -> bits amT2[w=m/32][k] (k contiguous) ----
__global__ void pack_am_k(const int* __restrict__ am, unsigned int* __restrict__ amT2) {
  int tid = blockIdx.x * blockDim.x + threadIdx.x;  // 131072 threads
  int k = tid & (SEQ - 1), w = tid >> 11;
  unsigned int bits = 0;
#pragma unroll 4
  for (int i = 0; i < 32; ++i)
    bits |= (am[(size_t)(w * 32 + i) * SEQ + k] != 0 ? 1u : 0u) << i;
  amT2[w * SEQ + k] = bits;
}

// ---- prepass: key_padding_mask (n,k) int -> bits kpmB[n][k/32] ----
__global__ void pack_kpm_k(const int* __restrict__ kpm, unsigned int* __restrict__ kpmB) {
  int tid = blockIdx.x * blockDim.x + threadIdx.x;  // 2048 threads
  if (tid >= NBATCH * 64) return;
  int n = tid >> 6, w = tid & 63;
  unsigned int bits = 0;
#pragma unroll 4
  for (int i = 0; i < 32; ++i)
    bits |= (kpm[n * SEQ + w * 32 + i] != 0 ? 1u : 0u) << i;
  kpmB[n * 64 + w] = bits;
}

// ---- main fused attention kernel ----
// block = 512 threads (8 waves). Each block: one batch n, 16 query rows.
// Wave w owns key columns [256w, 256w+256).
__global__ __launch_bounds__(512, 2)
void attn_main_k(const unsigned short* __restrict__ Qb,
                 const unsigned short* __restrict__ Kb,
                 const unsigned short* __restrict__ Vt,
                 const unsigned int* __restrict__ amT2,
                 const unsigned int* __restrict__ kpmB,
                 float* __restrict__ outO, float* __restrict__ outW) {
  __shared__ __align__(16) char smem[65536];  // P(bf16) 16 rows x 2048, XOR-swizzled

  const int n = blockIdx.y;
  const int row0 = blockIdx.x * 16;
  const int tid = threadIdx.x;
  const int wave = tid >> 6, lane = tid & 63;
  const int quad = lane >> 4, lq = lane & 15;
  const int colw = wave * 256;

  // Q A-fragments: A[m=lq][k = quad*8 + j] (+32 for second MFMA)
  const unsigned short* qp = Qb + ((size_t)(n * SEQ + row0 + lq)) * DHEAD + quad * 8;
  v8s a0 = *(const v8s*)qp;
  v8s a1 = *(const v8s*)(qp + 32);

  float p[64];
  float rsum[4] = {0.f, 0.f, 0.f, 0.f};
  const int amsh = row0 & 31;
  const int amw = row0 >> 5;

  // ---- Phase 1: S = QK^T/8, mask, exp; keep P in regs; accumulate row sums
#pragma unroll
  for (int kt = 0; kt < 16; ++kt) {
    const int col = colw + kt * 16 + lq;
    const unsigned short* kp = Kb + ((size_t)(n * SEQ + col)) * DHEAD + quad * 8;
    v8s b0 = *(const v8s*)kp;
    v8s b1 = *(const v8s*)(kp + 32);
    v4f c = {0.f, 0.f, 0.f, 0.f};
    c = __builtin_amdgcn_mfma_f32_16x16x32_bf16(a0, b0, c, 0, 0, 0);
    c = __builtin_amdgcn_mfma_f32_16x16x32_bf16(a1, b1, c, 0, 0, 0);
    // attn mask: one contiguous dword per lane (64B per 16 lanes, coalesced)
    unsigned int abits = amT2[amw * SEQ + col] >> amsh;
    // key padding mask: wave-uniform dword -> scalar load
    unsigned int kw = kpmB[n * 64 + (colw >> 5) + (kt >> 1)];
    unsigned int kbit = (kw >> ((kt & 1) * 16 + lq)) & 1u;
#pragma unroll
    for (int r = 0; r < 4; ++r) {
      unsigned int msk = kbit | ((abits >> (quad * 4 + r)) & 1u);
      float e = msk ? 0.f : __expf(c[r] * 0.125f);
      p[kt * 4 + r] = e;
      rsum[r] += e;
    }
  }

  // ---- Row-sum reduce: 16 lanes of quad -> all lanes; then cross-wave via LDS
#pragma unroll
  for (int r = 0; r < 4; ++r) {
    float s = rsum[r];
    s += __shfl_xor(s, 1);
    s += __shfl_xor(s, 2);
    s += __shfl_xor(s, 4);
    s += __shfl_xor(s, 8);
    rsum[r] = s;
  }
  float* wsum = (float*)smem;  // [8 waves][16 rows]
  if (lq == 0) {
#pragma unroll
    for (int r = 0; r < 4; ++r) wsum[wave * 16 + quad * 4 + r] = rsum[r];
  }
  __syncthreads();
  float rinv[4];
#pragma unroll
  for (int r = 0; r < 4; ++r) {
    float s = 0.f;
#pragma unroll
    for (int w = 0; w < 8; ++w) s += wsum[w * 16 + quad * 4 + r];
    rinv[r] = 1.0f / s;
  }
  __syncthreads();  // everyone done with wsum before P overwrites smem

  // ---- Phase 2: normalize, stash bf16 P in LDS (XOR-swizzled row-major)
  // byte = row*4096 + ((col/8 ^ (row&7))*16) + (col&7)*2
#pragma unroll
  for (int kt = 0; kt < 16; ++kt) {
    const int colL = colw + kt * 16 + lq;
#pragma unroll
    for (int r = 0; r < 4; ++r) {
      const int rr = quad * 4 + r;
      float pn = p[kt * 4 + r] * rinv[r];
      *(unsigned short*)(smem + rr * 4096 +
                         ((((colL >> 3) ^ (rr & 7)) << 4) | ((colL & 7) << 1))) = f2bf(pn);
    }
  }
  __syncthreads();

  // ---- Phase 3: O_partial = P(16x256) x V(256x64) via MFMA (LDS reads)
  v4f acc[4] = {{0.f,0.f,0.f,0.f},{0.f,0.f,0.f,0.f},{0.f,0.f,0.f,0.f},{0.f,0.f,0.f,0.f}};
#pragma unroll
  for (int ch = 0; ch < 8; ++ch) {
    const int cb = colw + ch * 32;
    v8s ap = *(const v8s*)(smem + lq * 4096 + (((((cb >> 3) + quad) ^ (lq & 7)) << 4)));
#pragma unroll
    for (int dt = 0; dt < 4; ++dt) {
      const unsigned short* vp =
          Vt + ((size_t)(n * DHEAD + dt * 16 + lq)) * SEQ + cb + quad * 8;
      v8s bp = *(const v8s*)vp;
      acc[dt] = __builtin_amdgcn_mfma_f32_16x16x32_bf16(ap, bp, acc[dt], 0, 0, 0);
    }
  }

  // ---- Phase 2b: coalesced vectorized outW write from LDS.
  // Wave w owns rows {2w, 2w+1}; each pass one wave writes 2048B contiguous.
  {
    float* wbase = outW + ((size_t)(n * SEQ + row0)) * SEQ;
#pragma unroll
    for (int ps = 0; ps < 8; ++ps) {
      const int row = wave * 2 + (ps & 1);
      const int cb8 = lane + ((ps >> 1) << 6);  // 16B-block index 0..255
      v8s pv = *(const v8s*)(smem + row * 4096 + ((cb8 ^ (row & 7)) << 4));
      float4 f0, f1;
      f0.x = bf2f(pv[0]); f0.y = bf2f(pv[1]); f0.z = bf2f(pv[2]); f0.w = bf2f(pv[3]);
      f1.x = bf2f(pv[4]); f1.y = bf2f(pv[5]); f1.z = bf2f(pv[6]); f1.w = bf2f(pv[7]);
      float* dst = wbase + (size_t)row * SEQ + (cb8 << 3);
      ((float4*)dst)[0] = f0;
      ((float4*)dst)[1] = f1;
    }
  }
  __syncthreads();

  // ---- Phase 4: cross-wave O reduction (8 partials of 16x64) through LDS
  float* olds = (float*)smem;  // [8][16][68] padded
#pragma unroll
  for (int dt = 0; dt < 4; ++dt)
#pragma unroll
    for (int r = 0; r < 4; ++r)
      olds[wave * 1088 + (quad * 4 + r) * 68 + dt * 16 + lq] = acc[dt][r];
  __syncthreads();
#pragma unroll
  for (int s = 0; s < 2; ++s) {
    int e = tid + s * 512;
    int row = e >> 6, d = e & 63;
    float a = 0.f;
#pragma unroll
    for (int w = 0; w < 8; ++w) a += olds[w * 1088 + row * 68 + d];
    outO[((size_t)(n * SEQ + row0 + row)) * DHEAD + d] = a;
  }
}

extern "C" void kernel_launch(void* const* d_in, const int* in_sizes, int n_in,
                              void* d_out, int out_size, void* d_ws, size_t ws_size,
                              hipStream_t stream) {
  const float* Q = (const float*)d_in[0];
  const float* K = (const float*)d_in[1];
  const float* V = (const float*)d_in[2];
  const int* kpm = (const int*)d_in[3];
  const int* am = (const int*)d_in[4];

  float* outO = (float*)d_out;
  float* outW = outO + (size_t)NBATCH * SEQ * DHEAD;  // 4,194,304 floats

  char* ws = (char*)d_ws;
  unsigned short* Qb = (unsigned short*)ws;                       // 8 MiB
  unsigned short* Kb = (unsigned short*)(ws + (8u << 20));        // 8 MiB
  unsigned short* Vt = (unsigned short*)(ws + (16u << 20));       // 8 MiB
  unsigned int* amT2 = (unsigned int*)(ws + (24u << 20));         // 512 KiB
  unsigned int* kpmB = (unsigned int*)(ws + (24u << 20) + (1u << 19));  // 8 KiB

  const int n4 = NBATCH * SEQ * DHEAD / 4;  // 1,048,576
  cvt_bf16_k<<<n4 / 256, 256, 0, stream>>>(Q, Qb, n4);
  cvt_bf16_k<<<n4 / 256, 256, 0, stream>>>(K, Kb, n4);
  vtrans_k<<<dim3(SEQ / 64, NBATCH), 256, 0, stream>>>(V, Vt);
  pack_am_k<<<(SEQ * 64) / 256, 256, 0, stream>>>(am, amT2);
  pack_kpm_k<<<8, 256, 0, stream>>>(kpm, kpmB);
  attn_main_k<<<dim3(SEQ / 16, NBATCH), 512, 0, stream>>>(Qb, Kb, Vt, amT2, kpmB,
                                                          outO, outW);
}